// Round 2
// baseline (1319.530 us; speedup 1.0000x reference)
//
#include <hip/hip_runtime.h>
#include <hip/hip_bf16.h>

typedef __bf16 bf16x8 __attribute__((ext_vector_type(8)));
typedef float f32x4 __attribute__((ext_vector_type(4)));

typedef __attribute__((address_space(1))) const void GVoid;
typedef __attribute__((address_space(3))) void LVoid;

static __device__ __forceinline__ float b2f(unsigned short u) {
    union { float f; unsigned int i; } x; x.i = ((unsigned int)u) << 16; return x.f;
}
static __device__ __forceinline__ unsigned short f2b(float f) {
    union { float f; unsigned int u; } x; x.f = f;
    unsigned int r = x.u + 0x7FFFu + ((x.u >> 16) & 1u);
    return (unsigned short)(r >> 16);
}

// ---------------- prep: weight hi/lo split, bias, relT (f32) ----------------
__global__ __launch_bounds__(256) void k_prep(const float* __restrict__ Wq, const float* __restrict__ Wk,
                                              const float* __restrict__ Wv, const float* __restrict__ bq,
                                              const float* __restrict__ bk, const float* __restrict__ bv,
                                              const float* __restrict__ relw, unsigned short* __restrict__ Wh,
                                              unsigned short* __restrict__ Wl, float* __restrict__ biasc,
                                              float* __restrict__ relT) {
    int o = blockIdx.x;
    if (o < 1024) {  // q,k rows: hi + lo split
        const float* src = (o < 512) ? (Wq + (long)o * 512) : (Wk + (long)(o - 512) * 512);
        for (int c = threadIdx.x; c < 512; c += 256) {
            float f = src[c];
            unsigned short hi = f2b(f);
            Wh[(long)o * 512 + c] = hi;
            Wl[(long)o * 512 + c] = f2b(f - b2f(hi));
        }
    } else if (o < 1536) {  // v rows: hi only
        const float* src = Wv + (long)(o - 1024) * 512;
        for (int c = threadIdx.x; c < 512; c += 256) Wh[(long)o * 512 + c] = f2b(src[c]);
    } else {
        for (int i = threadIdx.x; i < 1536; i += 256)
            biasc[i] = (i < 512) ? bq[i] : (i < 1024) ? bk[i - 512] : bv[i - 1024];
        // relT[h][i][d] = relw[h][d][i]  (f32)
        for (int idx = threadIdx.x; idx < 7168; idx += 256) {
            int h = idx / 1792, rem = idx % 1792, i = rem / 128, d = rem % 128;
            relT[idx] = relw[h * 1792 + d * 14 + i];
        }
    }
}

// ---------------- transpose: x[b][c][w] f32 -> xt_hi/xt_lo[(b,w)][c] bf16 ----------------
__global__ __launch_bounds__(256) void k_transpose(const float* __restrict__ x,
                                                   unsigned short* __restrict__ xh,
                                                   unsigned short* __restrict__ xlo, int b0) {
    __shared__ float xl[512 * 15];  // padded rows: xl[c*15 + w]
    const float* xb = x + (long)(b0 + blockIdx.x) * 7168;
    const float4* xb4 = (const float4*)xb;
    int tid = threadIdx.x;
#pragma unroll
    for (int it = 0; it < 7; ++it) {
        int f = tid + it * 256;
        float4 v = xb4[f];
        float vals[4] = {v.x, v.y, v.z, v.w};
        int e = f * 4;
#pragma unroll
        for (int j = 0; j < 4; ++j) {
            int ee = e + j;
            int c = (ee * 9363) >> 17;
            int w = ee - c * 14;
            xl[c * 15 + w] = vals[j];
        }
    }
    __syncthreads();
    unsigned short* hrow = xh + (long)blockIdx.x * 7168;
    unsigned short* lrow = xlo + (long)blockIdx.x * 7168;
#pragma unroll
    for (int it = 0; it < 14; ++it) {
        int p = tid + it * 256;
        int w = p >> 8, cp = p & 255;
        int c0 = cp * 2;
        float v0 = xl[c0 * 15 + w], v1 = xl[(c0 + 1) * 15 + w];
        unsigned int h0 = f2b(v0), h1 = f2b(v1);
        unsigned int l0 = f2b(v0 - b2f((unsigned short)h0));
        unsigned int l1 = f2b(v1 - b2f((unsigned short)h1));
        *(unsigned int*)(hrow + (long)w * 512 + c0) = h0 | (h1 << 16);
        *(unsigned int*)(lrow + (long)w * 512 + c0) = l0 | (l1 << 16);
    }
}

// ---------------- GEMM: 128x128 tile, BK=64, split-bf16 (TERMS=3) or plain (TERMS=1) ----------------
template <int TERMS>
__global__ __launch_bounds__(256) void k_gemm(const unsigned short* __restrict__ Ah,
                                              const unsigned short* __restrict__ Al,
                                              const unsigned short* __restrict__ Bh,
                                              const unsigned short* __restrict__ Bl,
                                              const float* __restrict__ bias,
                                              float* __restrict__ outf,
                                              unsigned short* __restrict__ outb, int Mtiles) {
    constexpr int NT = (TERMS == 3) ? 8 : 4;
    constexpr int NBUF = (TERMS == 3) ? 4 : 2;
    __shared__ unsigned short sm[NBUF][128 * 64];
    unsigned short* Ash = sm[0];
    unsigned short* Bsh = sm[1];

    int nwg = Mtiles * NT;
    int p = blockIdx.x;
    int t = (p & 7) * (nwg >> 3) + (p >> 3);
    int mt = t / NT, nt = t - mt * NT;
    long m0 = (long)mt * 128;
    int n0 = nt * 128;
    int tid = threadIdx.x, lane = tid & 63, wv = tid >> 6;
    int wr = wv >> 1, wc = wv & 1;
    int rrow = lane >> 3;
    int u = lane & 7;

    f32x4 acc[4][4];
#pragma unroll
    for (int i = 0; i < 4; ++i)
#pragma unroll
        for (int j = 0; j < 4; ++j) acc[i][j] = (f32x4){0.f, 0.f, 0.f, 0.f};

    for (int kt = 0; kt < 8; ++kt) {
        int kofs = kt * 64;
#pragma unroll
        for (int ti = 0; ti < 4; ++ti) {
            int chunk = wv * 4 + ti;
            int row = chunk * 8 + rrow;
            int colel = ((u ^ (row & 7)) << 3);
            long aofs = ((m0 + row) << 9) + kofs + colel;
            long bofs = ((long)(n0 + row) << 9) + kofs + colel;
            __builtin_amdgcn_global_load_lds((GVoid*)(Ah + aofs), (LVoid*)(Ash + chunk * 512), 16, 0, 0);
            __builtin_amdgcn_global_load_lds((GVoid*)(Bh + bofs), (LVoid*)(Bsh + chunk * 512), 16, 0, 0);
            if (TERMS == 3) {
                __builtin_amdgcn_global_load_lds((GVoid*)(Al + aofs), (LVoid*)(sm[2] + chunk * 512), 16, 0, 0);
                __builtin_amdgcn_global_load_lds((GVoid*)(Bl + bofs), (LVoid*)(sm[3] + chunk * 512), 16, 0, 0);
            }
        }
        asm volatile("s_waitcnt vmcnt(0)" ::: "memory");
        __syncthreads();
#pragma unroll
        for (int kk = 0; kk < 2; ++kk) {
            bf16x8 afh[4], bfh[4], afl[4], bfl[4];
            int kb = kk * 64 + ((lane >> 4) << 4);
#pragma unroll
            for (int mf = 0; mf < 4; ++mf) {
                int row = wr * 64 + mf * 16 + (lane & 15);
                int off = row * 128 + (kb ^ ((row & 7) << 4));
                afh[mf] = *(const bf16x8*)((const char*)Ash + off);
                if (TERMS == 3) afl[mf] = *(const bf16x8*)((const char*)sm[2] + off);
            }
#pragma unroll
            for (int nf = 0; nf < 4; ++nf) {
                int row = wc * 64 + nf * 16 + (lane & 15);
                int off = row * 128 + (kb ^ ((row & 7) << 4));
                bfh[nf] = *(const bf16x8*)((const char*)Bsh + off);
                if (TERMS == 3) bfl[nf] = *(const bf16x8*)((const char*)sm[3] + off);
            }
#pragma unroll
            for (int mf = 0; mf < 4; ++mf)
#pragma unroll
                for (int nf = 0; nf < 4; ++nf) {
                    acc[mf][nf] = __builtin_amdgcn_mfma_f32_16x16x32_bf16(afh[mf], bfh[nf], acc[mf][nf], 0, 0, 0);
                    if (TERMS == 3) {
                        acc[mf][nf] = __builtin_amdgcn_mfma_f32_16x16x32_bf16(afh[mf], bfl[nf], acc[mf][nf], 0, 0, 0);
                        acc[mf][nf] = __builtin_amdgcn_mfma_f32_16x16x32_bf16(afl[mf], bfh[nf], acc[mf][nf], 0, 0, 0);
                    }
                }
        }
        __syncthreads();
    }
#pragma unroll
    for (int nf = 0; nf < 4; ++nf) {
        int n = n0 + wc * 64 + nf * 16 + (lane & 15);
        float bv = bias[n];
#pragma unroll
        for (int mf = 0; mf < 4; ++mf) {
            long mg = m0 + wr * 64 + mf * 16 + ((lane >> 4) << 2);
#pragma unroll
            for (int r = 0; r < 4; ++r) {
                float val = acc[mf][nf][r] + bv;
                if (TERMS == 3) outf[(mg + r) * 1024 + n] = val;
                else            outb[(mg + r) * 512 + n] = f2b(val);
            }
        }
    }
}

// ---------------- attention: one (b, h) per 128-thread block, all f32 ----------------
__global__ __launch_bounds__(128) void k_attn(const float* __restrict__ qkf,
                                              const unsigned short* __restrict__ vb,
                                              const float* __restrict__ relT,
                                              float* __restrict__ out, int b0) {
    __shared__ float ql[14 * 128];
    __shared__ float kl[14 * 128];
    __shared__ float rell[14 * 128];
    __shared__ unsigned short vl[14 * 128];
    __shared__ float sl[14 * 16];
    int tid = threadIdx.x;
    int bl = blockIdx.x >> 2, h = blockIdx.x & 3;
    long mbase = (long)bl * 14;

    const float4* qk4 = (const float4*)qkf;
    const float4* rel4 = (const float4*)relT;
    const uint4* vb4 = (const uint4*)vb;
#pragma unroll
    for (int it = 0; it < 4; ++it) {
        int idx = tid + it * 128;
        if (idx < 448) {
            int w = idx >> 5, ch = idx & 31;
            long rowb = (mbase + w) * 256 + h * 32 + ch;
            *(float4*)&ql[w * 128 + ch * 4] = qk4[rowb];
            *(float4*)&kl[w * 128 + ch * 4] = qk4[rowb + 128];
            *(float4*)&rell[w * 128 + ch * 4] = rel4[h * 448 + w * 32 + ch];
        }
    }
#pragma unroll
    for (int it = 0; it < 2; ++it) {
        int idx = tid + it * 128;
        if (idx < 224) {
            int w = idx >> 4, ch = idx & 15;
            *(uint4*)&vl[w * 128 + ch * 8] = vb4[(mbase + w) * 64 + h * 16 + ch];
        }
    }
    __syncthreads();
    // scores s[i][j] = sum_d q[i,d]*k[j,d] + rel[i,d]*q[j,d]
#pragma unroll
    for (int it = 0; it < 2; ++it) {
        int s = tid + it * 128;
        if (s < 196) {
            int i = s / 14, j = s - i * 14;
            const float4* qi = (const float4*)&ql[i * 128];
            const float4* kj = (const float4*)&kl[j * 128];
            const float4* ri = (const float4*)&rell[i * 128];
            const float4* qj = (const float4*)&ql[j * 128];
            float acc = 0.f;
#pragma unroll
            for (int d4 = 0; d4 < 32; ++d4) {
                float4 a = qi[d4], b = kj[d4], c = ri[d4], e = qj[d4];
                acc += a.x * b.x + a.y * b.y + a.z * b.z + a.w * b.w;
                acc += c.x * e.x + c.y * e.y + c.z * e.z + c.w * e.w;
            }
            sl[i * 16 + j] = acc;
        }
    }
    __syncthreads();
    if (tid < 14) {
        float* row = &sl[tid * 16];
        float m = row[0];
#pragma unroll
        for (int j = 1; j < 14; ++j) m = fmaxf(m, row[j]);
        float ex[14]; float sum = 0.f;
#pragma unroll
        for (int j = 0; j < 14; ++j) { ex[j] = __expf(row[j] - m); sum += ex[j]; }
        float inv = 1.f / sum;
#pragma unroll
        for (int j = 0; j < 14; ++j) row[j] = ex[j] * inv;
    }
    __syncthreads();
    int d = tid;
    float vr[14];
#pragma unroll
    for (int j = 0; j < 14; ++j) vr[j] = b2f(vl[j * 128 + d]);
    float* orow = out + (((long)(b0 + bl) * 512 + h * 128 + d) * 14);
    float ob[14];
#pragma unroll
    for (int i = 0; i < 14; ++i) {
        const float* ar = &sl[i * 16];
        float a = 0.f;
#pragma unroll
        for (int j = 0; j < 14; ++j) a += vr[j] * ar[j];
        ob[i] = a;
    }
#pragma unroll
    for (int t2 = 0; t2 < 7; ++t2)
        *(float2*)(orow + t2 * 2) = make_float2(ob[2 * t2], ob[2 * t2 + 1]);
}

extern "C" void kernel_launch(void* const* d_in, const int* in_sizes, int n_in,
                              void* d_out, int out_size, void* d_ws, size_t ws_size,
                              hipStream_t stream) {
    const float* x    = (const float*)d_in[0];
    const float* Wq   = (const float*)d_in[1];
    const float* bq   = (const float*)d_in[2];
    const float* Wk   = (const float*)d_in[3];
    const float* bk   = (const float*)d_in[4];
    const float* Wv   = (const float*)d_in[5];
    const float* bv   = (const float*)d_in[6];
    const float* relw = (const float*)d_in[7];
    float* out = (float*)d_out;
    char* ws = (char*)d_ws;

    unsigned short* Wh    = (unsigned short*)ws;             // 1536*512*2 = 1572864
    unsigned short* Wl    = (unsigned short*)(ws + 1572864); // 1024*512*2 = 1048576
    float*          biasc = (float*)(ws + 2621440);          // 6144
    float*          relT  = (float*)(ws + 2627584);          // 28672
    const long WS_DATA = 2656256;

    // per-b: xh 14336 + xl 14336 + qkf 57344 + vb 14336 = 100352 bytes
    long avail = (long)ws_size - WS_DATA;
    long nbmax = avail / 100352;
    long NBc = (nbmax / 128) * 128;
    if (NBc > 8192) NBc = 8192;
    if (NBc < 128) NBc = 128;

    unsigned short* xh  = (unsigned short*)(ws + WS_DATA);
    unsigned short* xlo = xh + NBc * 7168;
    float*          qkf = (float*)(xlo + NBc * 7168);
    unsigned short* vb  = (unsigned short*)(qkf + NBc * 14336);

    k_prep<<<1537, 256, 0, stream>>>(Wq, Wk, Wv, bq, bk, bv, relw, Wh, Wl, biasc, relT);

    for (int b0 = 0; b0 < 8192; b0 += (int)NBc) {
        int nb = 8192 - b0; if (nb > NBc) nb = (int)NBc;
        k_transpose<<<nb, 256, 0, stream>>>(x, xh, xlo, b0);
        int Mtiles = (nb * 14) / 128;
        k_gemm<3><<<Mtiles * 8, 256, 0, stream>>>(xh, xlo, Wh, Wl, biasc, qkf, nullptr, Mtiles);
        k_gemm<1><<<Mtiles * 4, 256, 0, stream>>>(xh, nullptr, Wh + 1024 * 512, nullptr,
                                                  biasc + 1024, nullptr, vb, Mtiles);
        k_attn<<<nb * 4, 128, 0, stream>>>(qkf, vb, relT, out, b0);
    }
}

// Round 3
// 881.807 us; speedup vs baseline: 1.4964x; 1.4964x over previous
//
#include <hip/hip_runtime.h>
#include <hip/hip_bf16.h>

typedef __bf16 bf16x8 __attribute__((ext_vector_type(8)));
typedef float f32x4 __attribute__((ext_vector_type(4)));

typedef __attribute__((address_space(1))) const void GVoid;
typedef __attribute__((address_space(3))) void LVoid;

static __device__ __forceinline__ float b2f(unsigned short u) {
    union { float f; unsigned int i; } x; x.i = ((unsigned int)u) << 16; return x.f;
}
static __device__ __forceinline__ unsigned short f2b(float f) {
    union { float f; unsigned int u; } x; x.f = f;
    unsigned int r = x.u + 0x7FFFu + ((x.u >> 16) & 1u);
    return (unsigned short)(r >> 16);
}

// ---------------- prep ----------------
// blocks 0..1023   : Wq,Wk rows hi/lo split -> Wh/Wl rows 0..1023
// blocks 1024..1535: Wv rows hi -> Wvh
// blocks 1536..1591: Relq[h,i,:] = sum_d rel[h,d,i]*Wq[h*128+d,:]  (f32) -> hi/lo rows 1024..1079, + relbias
// block  1592      : biasc 0..1023 (bq,bk), 1080..1151 zero, 1152..1663 (bv); zero Wh/Wl rows 1080..1151
__global__ __launch_bounds__(256) void k_prep(const float* __restrict__ Wq, const float* __restrict__ Wk,
                                              const float* __restrict__ Wv, const float* __restrict__ bq,
                                              const float* __restrict__ bk, const float* __restrict__ bv,
                                              const float* __restrict__ relw, unsigned short* __restrict__ Wh,
                                              unsigned short* __restrict__ Wl, unsigned short* __restrict__ Wvh,
                                              float* __restrict__ biasc) {
    int o = blockIdx.x;
    int tid = threadIdx.x;
    if (o < 1024) {
        const float* src = (o < 512) ? (Wq + (long)o * 512) : (Wk + (long)(o - 512) * 512);
        for (int c = tid; c < 512; c += 256) {
            float f = src[c];
            unsigned short hi = f2b(f);
            Wh[(long)o * 512 + c] = hi;
            Wl[(long)o * 512 + c] = f2b(f - b2f(hi));
        }
    } else if (o < 1536) {
        const float* src = Wv + (long)(o - 1024) * 512;
        for (int c = tid; c < 512; c += 256) Wvh[(long)(o - 1024) * 512 + c] = f2b(src[c]);
    } else if (o < 1592) {
        int t = o - 1536, h = t / 14, i = t - h * 14;
#pragma unroll
        for (int cc = 0; cc < 2; ++cc) {
            int c = tid + cc * 256;
            float acc = 0.f;
            for (int d = 0; d < 128; ++d)
                acc += relw[h * 1792 + d * 14 + i] * Wq[(long)(h * 128 + d) * 512 + c];
            unsigned short hi = f2b(acc);
            Wh[(long)(1024 + t) * 512 + c] = hi;
            Wl[(long)(1024 + t) * 512 + c] = f2b(acc - b2f(hi));
        }
        if (tid == 0) {
            float acc = 0.f;
            for (int d = 0; d < 128; ++d) acc += relw[h * 1792 + d * 14 + i] * bq[h * 128 + d];
            biasc[1024 + t] = acc;
        }
    } else {
        for (int i = tid; i < 1664; i += 256) {
            if (i >= 1024 && i < 1080) continue;  // relbias written by Relq blocks
            float v = 0.f;
            if (i < 512) v = bq[i];
            else if (i < 1024) v = bk[i - 512];
            else if (i < 1152) v = 0.f;
            else v = bv[i - 1152];
            biasc[i] = v;
        }
        for (int idx = tid; idx < 72 * 512; idx += 256) {
            Wh[1080 * 512 + idx] = 0;
            Wl[1080 * 512 + idx] = 0;
        }
    }
}

// ---------------- transpose: x[b][c][w] f32 -> xh/xlo[(b,w)][c] bf16 ----------------
__global__ __launch_bounds__(256) void k_transpose(const float* __restrict__ x,
                                                   unsigned short* __restrict__ xh,
                                                   unsigned short* __restrict__ xlo, int b0) {
    __shared__ float xl[512 * 15];
    const float* xb = x + (long)(b0 + blockIdx.x) * 7168;
    const float4* xb4 = (const float4*)xb;
    int tid = threadIdx.x;
#pragma unroll
    for (int it = 0; it < 7; ++it) {
        int f = tid + it * 256;
        float4 v = xb4[f];
        float vals[4] = {v.x, v.y, v.z, v.w};
        int e = f * 4;
#pragma unroll
        for (int j = 0; j < 4; ++j) {
            int ee = e + j;
            int c = (ee * 9363) >> 17;
            int w = ee - c * 14;
            xl[c * 15 + w] = vals[j];
        }
    }
    __syncthreads();
    unsigned short* hrow = xh + (long)blockIdx.x * 7168;
    unsigned short* lrow = xlo + (long)blockIdx.x * 7168;
#pragma unroll
    for (int it = 0; it < 14; ++it) {
        int p = tid + it * 256;
        int w = p >> 8, cp = p & 255;
        int c0 = cp * 2;
        float v0 = xl[c0 * 15 + w], v1 = xl[(c0 + 1) * 15 + w];
        unsigned int h0 = f2b(v0), h1 = f2b(v1);
        unsigned int l0 = f2b(v0 - b2f((unsigned short)h0));
        unsigned int l1 = f2b(v1 - b2f((unsigned short)h1));
        *(unsigned int*)(hrow + (long)w * 512 + c0) = h0 | (h1 << 16);
        *(unsigned int*)(lrow + (long)w * 512 + c0) = l0 | (l1 << 16);
    }
}

// ---------------- GEMM: 128x128 tile, BK=64 ----------------
// TERMS=3: split-bf16 (A,B hi/lo), N=1152 (q,k,cp), f32 out (store n<1080)
// TERMS=1: plain bf16, N=512 (v), bf16 out
template <int TERMS>
__global__ __launch_bounds__(256) void k_gemm(const unsigned short* __restrict__ Ah,
                                              const unsigned short* __restrict__ Al,
                                              const unsigned short* __restrict__ Bh,
                                              const unsigned short* __restrict__ Bl,
                                              const float* __restrict__ bias,
                                              float* __restrict__ outf,
                                              unsigned short* __restrict__ outb, int Mtiles) {
    constexpr int NT = (TERMS == 3) ? 9 : 4;
    constexpr int OSTR = (TERMS == 3) ? 1152 : 512;
    constexpr int NBUF = (TERMS == 3) ? 4 : 2;
    __shared__ unsigned short sm[NBUF][128 * 64];
    unsigned short* Ash = sm[0];
    unsigned short* Bsh = sm[1];

    int nwg = Mtiles * NT;
    int p = blockIdx.x;
    int xcd = p & 7, orig8 = p >> 3;
    int q8 = nwg >> 3, r8 = nwg & 7;
    int t = (xcd < r8 ? xcd * (q8 + 1) : r8 * (q8 + 1) + (xcd - r8) * q8) + orig8;
    int mt = t / NT, nt = t - mt * NT;
    long m0 = (long)mt * 128;
    int n0 = nt * 128;
    int tid = threadIdx.x, lane = tid & 63, wv = tid >> 6;
    int wr = wv >> 1, wc = wv & 1;
    int rrow = lane >> 3;
    int u = lane & 7;

    f32x4 acc[4][4];
#pragma unroll
    for (int i = 0; i < 4; ++i)
#pragma unroll
        for (int j = 0; j < 4; ++j) acc[i][j] = (f32x4){0.f, 0.f, 0.f, 0.f};

    for (int kt = 0; kt < 8; ++kt) {
        int kofs = kt * 64;
#pragma unroll
        for (int ti = 0; ti < 4; ++ti) {
            int chunk = wv * 4 + ti;
            int row = chunk * 8 + rrow;
            int colel = ((u ^ (row & 7)) << 3);
            long aofs = ((m0 + row) << 9) + kofs + colel;
            long bofs = ((long)(n0 + row) << 9) + kofs + colel;
            __builtin_amdgcn_global_load_lds((GVoid*)(Ah + aofs), (LVoid*)(Ash + chunk * 512), 16, 0, 0);
            __builtin_amdgcn_global_load_lds((GVoid*)(Bh + bofs), (LVoid*)(Bsh + chunk * 512), 16, 0, 0);
            if (TERMS == 3) {
                __builtin_amdgcn_global_load_lds((GVoid*)(Al + aofs), (LVoid*)(sm[2] + chunk * 512), 16, 0, 0);
                __builtin_amdgcn_global_load_lds((GVoid*)(Bl + bofs), (LVoid*)(sm[3] + chunk * 512), 16, 0, 0);
            }
        }
        asm volatile("s_waitcnt vmcnt(0)" ::: "memory");
        __syncthreads();
#pragma unroll
        for (int kk = 0; kk < 2; ++kk) {
            bf16x8 afh[4], bfh[4], afl[4], bfl[4];
            int kb = kk * 64 + ((lane >> 4) << 4);
#pragma unroll
            for (int mf = 0; mf < 4; ++mf) {
                int row = wr * 64 + mf * 16 + (lane & 15);
                int off = row * 128 + (kb ^ ((row & 7) << 4));
                afh[mf] = *(const bf16x8*)((const char*)Ash + off);
                if (TERMS == 3) afl[mf] = *(const bf16x8*)((const char*)sm[2] + off);
            }
#pragma unroll
            for (int nf = 0; nf < 4; ++nf) {
                int row = wc * 64 + nf * 16 + (lane & 15);
                int off = row * 128 + (kb ^ ((row & 7) << 4));
                bfh[nf] = *(const bf16x8*)((const char*)Bsh + off);
                if (TERMS == 3) bfl[nf] = *(const bf16x8*)((const char*)sm[3] + off);
            }
#pragma unroll
            for (int mf = 0; mf < 4; ++mf)
#pragma unroll
                for (int nf = 0; nf < 4; ++nf) {
                    acc[mf][nf] = __builtin_amdgcn_mfma_f32_16x16x32_bf16(afh[mf], bfh[nf], acc[mf][nf], 0, 0, 0);
                    if (TERMS == 3) {
                        acc[mf][nf] = __builtin_amdgcn_mfma_f32_16x16x32_bf16(afh[mf], bfl[nf], acc[mf][nf], 0, 0, 0);
                        acc[mf][nf] = __builtin_amdgcn_mfma_f32_16x16x32_bf16(afl[mf], bfh[nf], acc[mf][nf], 0, 0, 0);
                    }
                }
        }
        __syncthreads();
    }
#pragma unroll
    for (int nf = 0; nf < 4; ++nf) {
        int n = n0 + wc * 64 + nf * 16 + (lane & 15);
        float bv = bias[n];
#pragma unroll
        for (int mf = 0; mf < 4; ++mf) {
            long mg = m0 + wr * 64 + mf * 16 + ((lane >> 4) << 2);
#pragma unroll
            for (int r = 0; r < 4; ++r) {
                float val = acc[mf][nf][r] + bv;
                if (TERMS == 3) { if (n < 1080) outf[(mg + r) * 1152 + n] = val; }
                else            outb[(mg + r) * 512 + n] = f2b(val);
            }
        }
    }
}

// ---------------- attention: one b per 512-thread block ----------------
// qkf row (b,w): [0..511]=q, [512..1023]=k, [1024..1079]=cp cols (h*14+i)
__global__ __launch_bounds__(512) void k_attn(const float* __restrict__ qkf,
                                              const unsigned short* __restrict__ vb,
                                              float* __restrict__ out, int b0) {
    __shared__ float qs[14 * 512];   // row w: 128 16B-units, unit idx ^ (w&7)
    __shared__ float ks[14 * 512];
    __shared__ float cps[56 * 16];   // [h*14+i][j]
    __shared__ float sl[56 * 16];
    __shared__ unsigned short vs[14 * 512];
    int tid = threadIdx.x;
    long mb = (long)blockIdx.x * 14;
    const float4* qk4 = (const float4*)qkf;  // 288 units per row
#pragma unroll
    for (int it = 0; it < 7; ++it) {
        int idx = tid + it * 512;
        int w = idx >> 8, c4 = idx & 255;
        float4 v = qk4[(mb + w) * 288 + c4];
        if (c4 < 128) *(float4*)&qs[w * 512 + ((c4 ^ (w & 7)) << 2)] = v;
        else {
            int uu = c4 - 128;
            *(float4*)&ks[w * 512 + ((uu ^ (w & 7)) << 2)] = v;
        }
    }
#pragma unroll
    for (int it = 0; it < 2; ++it) {
        int idx = tid + it * 512;
        if (idx < 784) {
            int w = idx / 56, tt = idx - w * 56;
            cps[tt * 16 + w] = qkf[(mb + w) * 1152 + 1024 + tt];
        }
    }
#pragma unroll
    for (int it = 0; it < 2; ++it) {
        int idx = tid + it * 512;
        if (idx < 896) {
            int w = idx >> 6, uu = idx & 63;
            *(uint4*)&vs[w * 512 + uu * 8] = *(const uint4*)&vb[(mb + w) * 512 + uu * 8];
        }
    }
    __syncthreads();
    // scores: 2x2 quad per thread. s[h][i][j] = q_i . k_j (+ cp)
    if (tid < 196) {
        int h = tid / 49, r = tid - h * 49;
        int i0 = (r / 7) * 2, j0 = (r - (r / 7) * 7) * 2;
        float a00 = 0.f, a01 = 0.f, a10 = 0.f, a11 = 0.f;
#pragma unroll
        for (int d4 = 0; d4 < 32; ++d4) {
            int uu = h * 32 + d4;
            float4 qa = *(const float4*)&qs[i0 * 512 + ((uu ^ (i0 & 7)) << 2)];
            float4 qb = *(const float4*)&qs[(i0 + 1) * 512 + ((uu ^ ((i0 + 1) & 7)) << 2)];
            float4 ka = *(const float4*)&ks[j0 * 512 + ((uu ^ (j0 & 7)) << 2)];
            float4 kb = *(const float4*)&ks[(j0 + 1) * 512 + ((uu ^ ((j0 + 1) & 7)) << 2)];
            a00 += qa.x * ka.x + qa.y * ka.y + qa.z * ka.z + qa.w * ka.w;
            a01 += qa.x * kb.x + qa.y * kb.y + qa.z * kb.z + qa.w * kb.w;
            a10 += qb.x * ka.x + qb.y * ka.y + qb.z * ka.z + qb.w * ka.w;
            a11 += qb.x * kb.x + qb.y * kb.y + qb.z * kb.z + qb.w * kb.w;
        }
        int base = (h * 14 + i0) * 16 + j0;
        sl[base] = a00 + cps[base];
        sl[base + 1] = a01 + cps[base + 1];
        sl[base + 16] = a10 + cps[base + 16];
        sl[base + 17] = a11 + cps[base + 17];
    }
    __syncthreads();
    if (tid < 56) {
        float* row = &sl[tid * 16];
        float m = row[0];
#pragma unroll
        for (int j = 1; j < 14; ++j) m = fmaxf(m, row[j]);
        float ex[14]; float sum = 0.f;
#pragma unroll
        for (int j = 0; j < 14; ++j) { ex[j] = __expf(row[j] - m); sum += ex[j]; }
        float inv = 1.f / sum;
#pragma unroll
        for (int j = 0; j < 14; ++j) row[j] = ex[j] * inv;
    }
    __syncthreads();
    // PV: c = tid (512 channels), h = c>>7
    int c = tid, h = c >> 7;
    float vr[14];
#pragma unroll
    for (int j = 0; j < 14; ++j) vr[j] = b2f(vs[j * 512 + c]);
    float* orow = out + (((long)(b0 + blockIdx.x) * 512 + c) * 14);
    float ob[14];
#pragma unroll
    for (int i = 0; i < 14; ++i) {
        const float* ar = &sl[(h * 14 + i) * 16];
        float a = 0.f;
#pragma unroll
        for (int j = 0; j < 14; ++j) a += vr[j] * ar[j];
        ob[i] = a;
    }
#pragma unroll
    for (int t2 = 0; t2 < 7; ++t2)
        *(float2*)(orow + t2 * 2) = make_float2(ob[2 * t2], ob[2 * t2 + 1]);
}

extern "C" void kernel_launch(void* const* d_in, const int* in_sizes, int n_in,
                              void* d_out, int out_size, void* d_ws, size_t ws_size,
                              hipStream_t stream) {
    const float* x    = (const float*)d_in[0];
    const float* Wq   = (const float*)d_in[1];
    const float* bq   = (const float*)d_in[2];
    const float* Wk   = (const float*)d_in[3];
    const float* bk   = (const float*)d_in[4];
    const float* Wv   = (const float*)d_in[5];
    const float* bv   = (const float*)d_in[6];
    const float* relw = (const float*)d_in[7];
    float* out = (float*)d_out;
    char* ws = (char*)d_ws;

    unsigned short* Wh   = (unsigned short*)ws;              // 1152*512*2 = 1179648
    unsigned short* Wl   = (unsigned short*)(ws + 1179648);  // 1179648
    unsigned short* Wvh  = (unsigned short*)(ws + 2359296);  // 524288
    float*          biasc = (float*)(ws + 2883584);          // 1664*4 = 6656
    const long WS_DATA = 2890240;

    // per-b: xh 14336 + xlo 14336 + qkf 64512 + vb 14336 = 107520 B
    long avail = (long)ws_size - WS_DATA;
    long nbmax = avail / 107520;
    long NBc = (nbmax / 128) * 128;
    if (NBc > 8192) NBc = 8192;
    if (NBc < 128) NBc = 128;

    unsigned short* xh  = (unsigned short*)(ws + WS_DATA);
    unsigned short* xlo = xh + NBc * 7168;
    float*          qkf = (float*)(xlo + NBc * 7168);
    unsigned short* vbw = (unsigned short*)(qkf + NBc * 16128);

    k_prep<<<1593, 256, 0, stream>>>(Wq, Wk, Wv, bq, bk, bv, relw, Wh, Wl, Wvh, biasc);

    for (int b0 = 0; b0 < 8192; b0 += (int)NBc) {
        int nb = 8192 - b0; if (nb > NBc) nb = (int)NBc;
        k_transpose<<<nb, 256, 0, stream>>>(x, xh, xlo, b0);
        int Mtiles = (nb * 14) / 128;
        k_gemm<3><<<Mtiles * 9, 256, 0, stream>>>(xh, xlo, Wh, Wl, biasc, qkf, nullptr, Mtiles);
        k_gemm<1><<<Mtiles * 4, 256, 0, stream>>>(xh, nullptr, Wvh, nullptr,
                                                  biasc + 1152, nullptr, vbw, Mtiles);
        k_attn<<<nb, 512, 0, stream>>>(qkf, vbw, out, b0);
    }
}